// Round 1
// baseline (431.516 us; speedup 1.0000x reference)
//
#include <hip/hip_runtime.h>

// Problem geometry (fixed by the reference: inputs (16, 4, 1024, 1024) fp32)
constexpr int NB = 16;
constexpr int NH = 1024;
constexpr int NW = 1024;

// Tile for the fused stencil kernel
constexpr int TX = 64;
constexpr int TY = 16;
constexpr int SW  = TX + 5;  // sT row stride (69) — breaks pow2 strides
constexpr int SNW = TX + 3;  // sN row stride (67)

// ---------------------------------------------------------------------------
// Kernel 1: uv_mag = max(|u|, |v|) over all batches (channels 0 and 1).
// u,v are contiguous per batch: 2*NH*NW floats starting at b*4*NH*NW.
// float4 loads; wave shuffle reduce; atomicMax on float bits (all values >=0).
// ---------------------------------------------------------------------------
__global__ __launch_bounds__(256) void uvmax_kernel(const float4* __restrict__ in,
                                                    unsigned int* __restrict__ outbits) {
    const size_t n4 = (size_t)NB * 2 * NH * NW / 4;   // 8M float4
    size_t tid = (size_t)blockIdx.x * blockDim.x + threadIdx.x;
    size_t stride = (size_t)gridDim.x * blockDim.x;
    float m = 0.0f;
    for (size_t i = tid; i < n4; i += stride) {
        size_t b   = i >> 19;                 // 2*NH*NW/4 = 512K float4 per batch
        size_t off = i & ((1u << 19) - 1);
        float4 x = in[b * (1u << 20) + off];  // batch stride = 4*NH*NW/4 = 1M float4
        m = fmaxf(m, fmaxf(fmaxf(fabsf(x.x), fabsf(x.y)),
                           fmaxf(fabsf(x.z), fabsf(x.w))));
    }
    // wave64 butterfly
    for (int o = 32; o > 0; o >>= 1) m = fmaxf(m, __shfl_down(m, o));
    __shared__ float sm[4];
    int lane = threadIdx.x & 63, wave = threadIdx.x >> 6;
    if (lane == 0) sm[wave] = m;
    __syncthreads();
    if (threadIdx.x == 0) {
        float mm = fmaxf(fmaxf(sm[0], sm[1]), fmaxf(sm[2], sm[3]));
        atomicMax(outbits, __float_as_uint(mm));
    }
}

// ---------------------------------------------------------------------------
// Kernel 2: fused advection + Laplacian step.
//   Phase A: stage T_prev tile with halo-2 into LDS (edge-clamped loads).
//   Phase B: compute T_new on tile with halo-1. For out-of-range halo points,
//            recompute at the CLAMPED coordinate (edge-replication of T_new),
//            indexing LDS by the clamped coordinate so the upwind stencil
//            reads the correct neighbors.
//   Phase C: 9-point Laplacian of T_new from LDS, add dt*(lap + RaQ), store.
// ---------------------------------------------------------------------------
__global__ __launch_bounds__(256) void step_kernel(const float* __restrict__ in,
                                                   const unsigned int* __restrict__ maxbits,
                                                   float* __restrict__ out) {
    __shared__ float sT[(TY + 4) * SW];
    __shared__ float sN[(TY + 2) * SNW];

    const int b  = blockIdx.z;
    const int x0 = blockIdx.x * TX;
    const int y0 = blockIdx.y * TY;

    const size_t cs = (size_t)NH * NW;
    const float* Uc = in + (size_t)b * 4 * cs;
    const float* Vc = Uc + cs;
    const float* Tc = Uc + 2 * cs;
    const float* Rc = Uc + 3 * cs;

    const float dx  = 1.0f / 126.0f;
    const float dx2 = dx * dx;
    const float uv_mag = __uint_as_float(*maxbits);
    const float dt_adv = 0.5f * 0.1f * dx / uv_mag;
    const float dt_dif = 0.5f * (dx2 * dx2) / (dx2 + dx2);
    const float dt = fminf(dt_adv, dt_dif);

    const int tid = threadIdx.x;

    // Phase A: T_prev tile with halo 2, edge-clamped
    for (int idx = tid; idx < (TY + 4) * (TX + 4); idx += 256) {
        int j = idx / (TX + 4);
        int i = idx - j * (TX + 4);
        int gy = min(max(y0 + j - 2, 0), NH - 1);
        int gx = min(max(x0 + i - 2, 0), NW - 1);
        sT[j * SW + i] = Tc[(size_t)gy * NW + gx];
    }
    __syncthreads();

    // Phase B: T_new on halo-1 grid
    for (int idx = tid; idx < (TY + 2) * (TX + 2); idx += 256) {
        int ty = idx / (TX + 2);
        int tx = idx - ty * (TX + 2);
        int gy = y0 + ty - 1, gx = x0 + tx - 1;
        int cgy = min(max(gy, 0), NH - 1);
        int cgx = min(max(gx, 0), NW - 1);
        int lj = cgy - y0 + 2;
        int li = cgx - x0 + 2;
        float c  = sT[lj * SW + li];
        float lf = sT[lj * SW + li - 1];
        float rt = sT[lj * SW + li + 1];
        float tp = sT[(lj - 1) * SW + li];
        float bt = sT[(lj + 1) * SW + li];
        float u = Uc[(size_t)cgy * NW + cgx];
        float v = Vc[(size_t)cgy * NW + cgx];
        float dT_dx = (u > 0.0f) ? (c - lf) / dx : ((u < 0.0f) ? (rt - c) / dx : 0.0f);
        float dT_dy = (v > 0.0f) ? (c - tp) / dx : ((v < 0.0f) ? (bt - c) / dx : 0.0f);
        sN[ty * SNW + tx] = c + dt * (-u * dT_dx - v * dT_dy);
    }
    __syncthreads();

    // Phase C: Laplacian + source, store
    float* Ob = out + (size_t)b * cs;
    for (int idx = tid; idx < TY * TX; idx += 256) {
        int ty = idx / TX;
        int tx = idx - ty * TX;
        int gy = y0 + ty, gx = x0 + tx;
        const float* r0 = &sN[ty * SNW + tx];
        const float* r1 = r0 + SNW;
        const float* r2 = r1 + SNW;
        float lap = 0.25f * (r0[0] + 2.0f * r0[1] + r0[2]
                           + 2.0f * r1[0] - 12.0f * r1[1] + 2.0f * r1[2]
                           + r2[0] + 2.0f * r2[1] + r2[2]) / dx2;
        Ob[(size_t)gy * NW + gx] = r1[1] + dt * (lap + Rc[(size_t)gy * NW + gx]);
    }

    // dt scalar output (last element)
    if (b == 0 && blockIdx.x == 0 && blockIdx.y == 0 && tid == 0) {
        out[(size_t)NB * cs] = dt;
    }
}

extern "C" void kernel_launch(void* const* d_in, const int* in_sizes, int n_in,
                              void* d_out, int out_size, void* d_ws, size_t ws_size,
                              hipStream_t stream) {
    const float* in = (const float*)d_in[0];
    float* out = (float*)d_out;
    unsigned int* maxbits = (unsigned int*)d_ws;

    // ws is re-poisoned to 0xAA before every timed call — zero the scalar
    hipMemsetAsync(d_ws, 0, sizeof(unsigned int), stream);

    uvmax_kernel<<<1024, 256, 0, stream>>>((const float4*)in, maxbits);

    dim3 grid(NW / TX, NH / TY, NB);
    step_kernel<<<grid, 256, 0, stream>>>(in, maxbits, out);
}

// Round 2
// 421.891 us; speedup vs baseline: 1.0228x; 1.0228x over previous
//
#include <hip/hip_runtime.h>

// Problem geometry (fixed by reference: inputs (16, 4, 1024, 1024) fp32)
constexpr int NB = 16;
constexpr int NH = 1024;
constexpr int NW = 1024;

// Stencil tile: 128x32 per 256-thread block (16 outputs/thread)
constexpr int TX = 128;
constexpr int TY = 32;
constexpr int NPART = 1024;   // reduction partials in d_ws

// sT: T_prev tile, rows gy=y0-2..y0+33 (36), cols gx=x0-4..x0+131 (136 floats)
//     left halo widened 2->4 so x0-4 stays 16B-aligned for float4 loads.
constexpr int RA  = TY + 4;        // 36 rows
constexpr int CA  = TX + 8;        // 136 floats
constexpr int CA4 = CA / 4;        // 34 float4 per row
constexpr int STW = CA + 4;        // 140: pad keeps float4 alignment, breaks pow2
// sN: T_new tile, rows gy=y0-1..y0+32 (34), same 136-wide cols, stride 140
constexpr int RB  = TY + 2;        // 34 rows
constexpr int SNW = 140;

// ---------------------------------------------------------------------------
// Kernel 1: per-block max(|u|,|v|) partials -> ws[0..NPART). No atomics, no
// memset needed: all NPART slots are plain-stored every call.
// u,v are the first 2*NH*NW floats of each batch (batch stride 4*NH*NW).
// ---------------------------------------------------------------------------
__global__ __launch_bounds__(256) void uvmax_kernel(const float4* __restrict__ in,
                                                    float* __restrict__ part) {
    const size_t n4 = (size_t)NB * 2 * NH * NW / 4;      // 8M float4
    size_t i0 = (size_t)blockIdx.x * blockDim.x + threadIdx.x;
    size_t stride = (size_t)gridDim.x * blockDim.x;
    float m = 0.0f;
    for (size_t i = i0; i < n4; i += stride) {
        size_t b   = i >> 19;                  // 2*NH*NW/4 = 2^19 f4 per batch
        size_t off = i & ((1u << 19) - 1);
        float4 x = in[(b << 20) + off];        // batch stride = 2^20 f4
        m = fmaxf(m, fmaxf(fmaxf(fabsf(x.x), fabsf(x.y)),
                           fmaxf(fabsf(x.z), fabsf(x.w))));
    }
    for (int o = 32; o > 0; o >>= 1) m = fmaxf(m, __shfl_down(m, o));
    __shared__ float sm[4];
    if ((threadIdx.x & 63) == 0) sm[threadIdx.x >> 6] = m;
    __syncthreads();
    if (threadIdx.x == 0)
        part[blockIdx.x] = fmaxf(fmaxf(sm[0], sm[1]), fmaxf(sm[2], sm[3]));
}

// ---------------------------------------------------------------------------
// Kernel 2: fused advection + Laplacian. Each block: reduce partials -> dt,
// stage T_prev (halo 2) in LDS, compute T_new (halo 1) in LDS with
// edge-replication via clamped-coordinate indexing, then 9-pt Laplacian.
// All in-bounds global traffic is aligned float4.
// ---------------------------------------------------------------------------
__global__ __launch_bounds__(256) void step_kernel(const float* __restrict__ in,
                                                   const float* __restrict__ part,
                                                   float* __restrict__ out) {
    __shared__ float sT[RA * STW];
    __shared__ float sN[RB * SNW];
    __shared__ float sred[4];
    __shared__ float sdt;

    const int tid = threadIdx.x;

    // --- dt from the NPART partials (1 float4/thread, L2-resident) ---
    {
        float4 p = ((const float4*)part)[tid];            // 256*4 = 1024
        float m = fmaxf(fmaxf(p.x, p.y), fmaxf(p.z, p.w));
        for (int o = 32; o > 0; o >>= 1) m = fmaxf(m, __shfl_down(m, o));
        if ((tid & 63) == 0) sred[tid >> 6] = m;
        __syncthreads();
        if (tid == 0) {
            float mm = fmaxf(fmaxf(sred[0], sred[1]), fmaxf(sred[2], sred[3]));
            const float dx = 1.0f / 126.0f, dx2 = dx * dx;
            float dta = 0.5f * 0.1f * dx / mm;
            float dtd = 0.5f * (dx2 * dx2) / (dx2 + dx2);
            sdt = fminf(dta, dtd);
        }
        __syncthreads();
    }
    const float dt = sdt;

    const int b  = blockIdx.z;
    const int x0 = blockIdx.x * TX;
    const int y0 = blockIdx.y * TY;
    const size_t cs = (size_t)NH * NW;
    const float* Uc = in + (size_t)b * 4 * cs;
    const float* Vc = Uc + cs;
    const float* Tc = Uc + 2 * cs;
    const float* Rc = Uc + 3 * cs;

    const float dx    = 1.0f / 126.0f;
    const float dt_dx = dt / dx;             // fold /dx into one multiplier
    const float q_dx2 = 0.25f / (dx * dx);   // fold 0.25/dx^2

    // --- Phase A: stage T_prev, rows clamped in y; vector loads unless the
    //     float4 spans an x edge (only x-edge blocks take the scalar path) ---
    for (int idx = tid; idx < RA * CA4; idx += 256) {
        int j  = idx / CA4;
        int cc = idx - j * CA4;
        int gy  = min(max(y0 + j - 2, 0), NH - 1);
        int gxb = x0 - 4 + 4 * cc;
        float4 t4;
        if (gxb >= 0 && gxb + 3 < NW) {
            t4 = *(const float4*)&Tc[(size_t)gy * NW + gxb];
        } else {
            float* f = (float*)&t4;
            #pragma unroll
            for (int k = 0; k < 4; k++) {
                int cgx = min(max(gxb + k, 0), NW - 1);
                f[k] = Tc[(size_t)gy * NW + cgx];
            }
        }
        *(float4*)&sT[j * STW + 4 * cc] = t4;
    }
    __syncthreads();

    // --- Phase B: T_new on halo-1 grid (plus 3 junk cols at the far-left
    //     pad, never read by Phase C). Halo points recomputed at CLAMPED
    //     coords -> correct edge replication of T_new. ---
    for (int idx = tid; idx < RB * CA4; idx += 256) {
        int ty = idx / CA4;
        int cc = idx - ty * CA4;
        int gy  = y0 + ty - 1;
        int cgy = min(max(gy, 0), NH - 1);
        int lj  = cgy - y0 + 2;              // in [1, 34]
        int gxb = x0 - 4 + 4 * cc;
        size_t rowo = (size_t)cgy * NW;
        bool vec = (gxb >= 0 && gxb + 3 < NW);
        float4 u4, v4;
        if (vec) {
            u4 = *(const float4*)&Uc[rowo + gxb];
            v4 = *(const float4*)&Vc[rowo + gxb];
        }
        float tn[4];
        #pragma unroll
        for (int k = 0; k < 4; k++) {
            int cgx = min(max(gxb + k, 0), NW - 1);
            float uu = vec ? ((const float*)&u4)[k] : Uc[rowo + cgx];
            float vv = vec ? ((const float*)&v4)[k] : Vc[rowo + cgx];
            int li = cgx - x0 + 4;           // index LDS by clamped coord
            const float* s = &sT[lj * STW + li];
            float c = s[0];
            float selx = (uu > 0.f) ? (c - s[-1])
                       : ((uu < 0.f) ? (s[1] - c) : 0.f);
            float sely = (vv > 0.f) ? (c - s[-STW])
                       : ((vv < 0.f) ? (s[STW] - c) : 0.f);
            tn[k] = c - dt_dx * (uu * selx + vv * sely);
        }
        *(float4*)&sN[ty * SNW + 4 * cc] = make_float4(tn[0], tn[1], tn[2], tn[3]);
    }
    __syncthreads();

    // --- Phase C: 9-pt Laplacian of T_new + source, aligned float4 I/O ---
    float* Ob = out + b * cs;
    for (int idx = tid; idx < TY * (TX / 4); idx += 256) {
        int ty = idx / (TX / 4);
        int cc = idx - ty * (TX / 4);
        int gy  = y0 + ty;
        int gxb = x0 + 4 * cc;
        const float* r0 = &sN[ty * SNW + 4 + 4 * cc];   // row gy-1
        const float* r1 = r0 + SNW;                     // row gy
        const float* r2 = r1 + SNW;                     // row gy+1
        float4 rq = *(const float4*)&Rc[(size_t)gy * NW + gxb];
        float o[4];
        #pragma unroll
        for (int k = 0; k < 4; k++) {
            float lap = (        r0[k - 1] + 2.f * r0[k] +        r0[k + 1]
                        + 2.f * r1[k - 1] - 12.f * r1[k] + 2.f * r1[k + 1]
                        +       r2[k - 1] + 2.f * r2[k] +        r2[k + 1]) * q_dx2;
            o[k] = r1[k] + dt * (lap + ((const float*)&rq)[k]);
        }
        *(float4*)&Ob[(size_t)gy * NW + gxb] = make_float4(o[0], o[1], o[2], o[3]);
    }

    // dt scalar (last output element)
    if (b == 0 && blockIdx.x == 0 && blockIdx.y == 0 && tid == 0)
        out[(size_t)NB * cs] = dt;
}

extern "C" void kernel_launch(void* const* d_in, const int* in_sizes, int n_in,
                              void* d_out, int out_size, void* d_ws, size_t ws_size,
                              hipStream_t stream) {
    const float* in = (const float*)d_in[0];
    float* out = (float*)d_out;
    float* part = (float*)d_ws;   // NPART floats, fully overwritten each call

    uvmax_kernel<<<NPART, 256, 0, stream>>>((const float4*)in, part);

    dim3 grid(NW / TX, NH / TY, NB);   // (8, 32, 16)
    step_kernel<<<grid, 256, 0, stream>>>(in, part, out);
}